// Round 1
// baseline (445.991 us; speedup 1.0000x reference)
//
#include <hip/hip_runtime.h>

// RNN: B=2048 chains, T=1024 steps, H=64, I=1.
// One wave (64 lanes) per batch chain. Lane i computes h[i] each step.
// W_hh row i lives in lane i's VGPRs; h broadcast via LDS (in-order DS pipe,
// single wave per block -> no barriers needed).

constexpr int T_STEPS = 1024;
constexpr int H = 64;

__global__ __launch_bounds__(64) void rnn_fused(
    const float* __restrict__ x,      // [B, T, 1]
    const float* __restrict__ W_ih,   // [H, 1]
    const float* __restrict__ W_hh,   // [H, H] row-major
    const float* __restrict__ b_ih,   // [H]
    const float* __restrict__ b_hh,   // [H]
    const float* __restrict__ W_out,  // [1, H]
    const float* __restrict__ b_out,  // [1]
    float* __restrict__ out)          // [B, 1]
{
    const int b    = blockIdx.x;
    const int lane = threadIdx.x;     // 0..63

    __shared__ float4 xs4[T_STEPS / 4];   // 4 KiB: x[b, :]
    __shared__ float4 hs4[2][H / 4];      // 512 B: double-buffered h

    // Stage x[b, :] into LDS, coalesced float4 (4 iters x 64 lanes).
    const float4* xrow = reinterpret_cast<const float4*>(x + (size_t)b * T_STEPS);
    #pragma unroll
    for (int k = 0; k < T_STEPS / 4 / H; ++k)
        xs4[lane + H * k] = xrow[lane + H * k];

    // Lane i keeps W_hh row i in registers (64 VGPRs).
    float w[H];
    const float4* wrow = reinterpret_cast<const float4*>(W_hh + lane * H);
    #pragma unroll
    for (int k = 0; k < H / 4; ++k) {
        float4 v = wrow[k];
        w[4 * k + 0] = v.x; w[4 * k + 1] = v.y;
        w[4 * k + 2] = v.z; w[4 * k + 3] = v.w;
    }
    const float wih  = W_ih[lane];
    const float bias = b_ih[lane] + b_hh[lane];

    // h0 = 0
    if (lane < H / 4) hs4[0][lane] = float4{0.f, 0.f, 0.f, 0.f};

    const float* xs    = reinterpret_cast<const float*>(xs4);
    float*       hflat = reinterpret_cast<float*>(hs4);

    float hn  = 0.f;
    int   cur = 0;
    for (int t = 0; t < T_STEPS; ++t) {
        const float xv = xs[t];                       // uniform broadcast read
        float a0 = fmaf(xv, wih, bias);
        float a1 = 0.f, a2 = 0.f, a3 = 0.f;
        #pragma unroll
        for (int jj = 0; jj < H / 4; ++jj) {
            const float4 hv = hs4[cur][jj];           // ds_read_b128 broadcast
            a0 = fmaf(hv.x, w[4 * jj + 0], a0);
            a1 = fmaf(hv.y, w[4 * jj + 1], a1);
            a2 = fmaf(hv.z, w[4 * jj + 2], a2);
            a3 = fmaf(hv.w, w[4 * jj + 3], a3);
        }
        const float s = (a0 + a1) + (a2 + a3);
        // tanh(s) = 1 - 2/(exp(2s)+1); saturates correctly for |s| large.
        const float e = __expf(2.f * s);
        hn = 1.f - 2.f * __builtin_amdgcn_rcpf(e + 1.f);
        hflat[(cur ^ 1) * H + lane] = hn;             // write h_new to other buffer
        cur ^= 1;
    }

    // out[b] = sigmoid(sum_i h[i] * W_out[i] + b_out)
    float v = hn * W_out[lane];
    #pragma unroll
    for (int off = 32; off; off >>= 1)
        v += __shfl_xor(v, off);
    if (lane == 0)
        out[b] = 1.f / (1.f + __expf(-(v + b_out[0])));
}

extern "C" void kernel_launch(void* const* d_in, const int* in_sizes, int n_in,
                              void* d_out, int out_size, void* d_ws, size_t ws_size,
                              hipStream_t stream)
{
    const float* x     = (const float*)d_in[0];
    const float* W_ih  = (const float*)d_in[1];
    const float* W_hh  = (const float*)d_in[2];
    const float* b_ih  = (const float*)d_in[3];
    const float* b_hh  = (const float*)d_in[4];
    const float* W_out = (const float*)d_in[5];
    const float* b_out = (const float*)d_in[6];
    float* out = (float*)d_out;

    const int B = out_size;  // [B,1] -> B blocks, one wave each
    rnn_fused<<<B, 64, 0, stream>>>(x, W_ih, W_hh, b_ih, b_hh, W_out, b_out, out);
}

// Round 2
// 437.224 us; speedup vs baseline: 1.0201x; 1.0201x over previous
//
#include <hip/hip_runtime.h>

// RNN: B=2048 chains, T=1024 steps, H=64, I=1.
// One wave per chain, lane i computes h[i]. W_hh row i in lane i's VGPRs
// (launch_bounds(64,2) -> 256-reg budget, matches grid's 2 waves/SIMD).
// h double-buffered in LDS with STATIC buffer names (t-loop unrolled x2)
// so all ds_read offsets are immediates. Single wave/block -> no barriers
// (LDS ops are in-order within a wave).

constexpr int T_STEPS = 1024;
constexpr int H = 64;

__global__ __launch_bounds__(64, 2) void rnn_fused(
    const float* __restrict__ x,      // [B, T, 1]
    const float* __restrict__ W_ih,   // [H, 1]
    const float* __restrict__ W_hh,   // [H, H] row-major
    const float* __restrict__ b_ih,   // [H]
    const float* __restrict__ b_hh,   // [H]
    const float* __restrict__ W_out,  // [1, H]
    const float* __restrict__ b_out,  // [1]
    float* __restrict__ out)          // [B, 1]
{
    const int b    = blockIdx.x;
    const int lane = threadIdx.x;     // 0..63

    __shared__ float4 xs4[T_STEPS / 4];   // 4 KiB: x[b, :]
    __shared__ float  hA[H];              // ping
    __shared__ float  hB[H];              // pong

    // Stage x[b, :] into LDS, coalesced float4.
    const float4* xrow = reinterpret_cast<const float4*>(x + (size_t)b * T_STEPS);
    #pragma unroll
    for (int k = 0; k < T_STEPS / 4 / H; ++k)
        xs4[lane + H * k] = xrow[lane + H * k];

    // Lane i keeps W_hh row i in 64 arch VGPRs.
    float w[H];
    const float4* wrow = reinterpret_cast<const float4*>(W_hh + lane * H);
    #pragma unroll
    for (int k = 0; k < H / 4; ++k) {
        float4 v = wrow[k];
        w[4 * k + 0] = v.x; w[4 * k + 1] = v.y;
        w[4 * k + 2] = v.z; w[4 * k + 3] = v.w;
    }
    const float wih  = W_ih[lane];
    const float bias = b_ih[lane] + b_hh[lane];

    hA[lane] = 0.f;   // h0 = 0

    const float* xs = reinterpret_cast<const float*>(xs4);

    // One recurrence step: s = xp + <W_hh[lane,:], hbuf>; return tanh(s).
    // 8 accumulators -> dep-chain depth 8.
    auto step = [&](float xv, const float* __restrict__ hbuf) -> float {
        const float4* h4 = reinterpret_cast<const float4*>(hbuf);
        float a0 = fmaf(xv, wih, bias);
        float a1 = 0.f, a2 = 0.f, a3 = 0.f;
        float a4 = 0.f, a5 = 0.f, a6 = 0.f, a7 = 0.f;
        #pragma unroll
        for (int jj = 0; jj < H / 4; jj += 2) {
            const float4 u = h4[jj];       // ds_read_b128, uniform broadcast
            const float4 v = h4[jj + 1];
            a0 = fmaf(u.x, w[4 * jj + 0], a0);
            a1 = fmaf(u.y, w[4 * jj + 1], a1);
            a2 = fmaf(u.z, w[4 * jj + 2], a2);
            a3 = fmaf(u.w, w[4 * jj + 3], a3);
            a4 = fmaf(v.x, w[4 * jj + 4], a4);
            a5 = fmaf(v.y, w[4 * jj + 5], a5);
            a6 = fmaf(v.z, w[4 * jj + 6], a6);
            a7 = fmaf(v.w, w[4 * jj + 7], a7);
        }
        const float s = ((a0 + a1) + (a2 + a3)) + ((a4 + a5) + (a6 + a7));
        // tanh(s) = 1 - 2/(exp(2s)+1); saturates correctly for |s| large.
        const float e = __expf(2.f * s);
        return 1.f - 2.f * __builtin_amdgcn_rcpf(e + 1.f);
    };

    float hn = 0.f;
    for (int t = 0; t < T_STEPS; t += 2) {
        hn = step(xs[t], hA);
        hB[lane] = hn;                 // static address: ds_write immediate
        hn = step(xs[t + 1], hB);
        hA[lane] = hn;
    }

    // out[b] = sigmoid(sum_i h[i] * W_out[i] + b_out)
    float v = hn * W_out[lane];
    #pragma unroll
    for (int off = 32; off; off >>= 1)
        v += __shfl_xor(v, off);
    if (lane == 0)
        out[b] = 1.f / (1.f + __expf(-(v + b_out[0])));
}

extern "C" void kernel_launch(void* const* d_in, const int* in_sizes, int n_in,
                              void* d_out, int out_size, void* d_ws, size_t ws_size,
                              hipStream_t stream)
{
    const float* x     = (const float*)d_in[0];
    const float* W_ih  = (const float*)d_in[1];
    const float* W_hh  = (const float*)d_in[2];
    const float* b_ih  = (const float*)d_in[3];
    const float* b_hh  = (const float*)d_in[4];
    const float* W_out = (const float*)d_in[5];
    const float* b_out = (const float*)d_in[6];
    float* out = (float*)d_out;

    const int B = out_size;  // one wave per chain
    rnn_fused<<<B, 64, 0, stream>>>(x, W_ih, W_hh, b_ih, b_hh, W_out, b_out, out);
}

// Round 3
// 389.899 us; speedup vs baseline: 1.1439x; 1.1214x over previous
//
#include <hip/hip_runtime.h>

// RNN: B=2048 chains, T=1024 steps, H=64, I=1.
// One wave per chain. Lane (og=lane>>2, kg=lane&3) computes outputs
// [4og,4og+4) over k-slice [16kg,16kg+16): W tile 4x16 in 64 VGPRs.
// Per step each lane reads only 64 B of h from LDS (4x less DS delivery
// than full broadcast -- the round-1/2 bottleneck). Cross-kg reduction
// via DPP quad_perm butterflies (VALU pipe, no LDS). 16 masked lanes
// write h back (one conflict-free ds_write_b128). Single wave per block
// -> DS ops in order, no barriers.

constexpr int T_STEPS = 1024;
constexpr int H = 64;

__device__ __forceinline__ float dpp_add_xor1(float x) {
    int y = __builtin_amdgcn_mov_dpp(__builtin_bit_cast(int, x), 0xB1, 0xF, 0xF, true);
    return x + __builtin_bit_cast(float, y);   // quad_perm [1,0,3,2]
}
__device__ __forceinline__ float dpp_add_xor2(float x) {
    int y = __builtin_amdgcn_mov_dpp(__builtin_bit_cast(int, x), 0x4E, 0xF, 0xF, true);
    return x + __builtin_bit_cast(float, y);   // quad_perm [2,3,0,1]
}

__device__ __forceinline__ float tanh_fast(float s) {
    // tanh(s) = 1 - 2/(exp(2s)+1); saturates correctly for |s| large.
    const float e = __expf(2.f * s);
    return 1.f - 2.f * __builtin_amdgcn_rcpf(e + 1.f);
}

__global__ __launch_bounds__(64, 2) void rnn_fused(
    const float* __restrict__ x,      // [B, T, 1]
    const float* __restrict__ W_ih,   // [H, 1]
    const float* __restrict__ W_hh,   // [H, H] row-major
    const float* __restrict__ b_ih,   // [H]
    const float* __restrict__ b_hh,   // [H]
    const float* __restrict__ W_out,  // [1, H]
    const float* __restrict__ b_out,  // [1]
    float* __restrict__ out)          // [B, 1]
{
    const int b    = blockIdx.x;
    const int lane = threadIdx.x;     // 0..63
    const int og   = lane >> 2;       // output group: outputs [4og, 4og+4)
    const int kg   = lane & 3;        // k group: k in [16kg, 16kg+16)

    __shared__ float4 xs4[T_STEPS / 4];   // 4 KiB: x[b, :]
    __shared__ float4 hA[H / 4];          // ping (64 floats)
    __shared__ float4 hB[H / 4];          // pong

    // Stage x[b, :] into LDS, coalesced float4.
    const float4* xrow = reinterpret_cast<const float4*>(x + (size_t)b * T_STEPS);
    #pragma unroll
    for (int k = 0; k < T_STEPS / 4 / 64; ++k)
        xs4[lane + 64 * k] = xrow[lane + 64 * k];

    // W tile: rows 4og..4og+3, cols 16kg..16kg+15 (16 float4 = 64 VGPRs).
    float4 w[4][4];
    #pragma unroll
    for (int r = 0; r < 4; ++r)
        #pragma unroll
        for (int c = 0; c < 4; ++c)
            w[r][c] = *reinterpret_cast<const float4*>(
                W_hh + (size_t)(4 * og + r) * H + 16 * kg + 4 * c);

    // xp coefficients masked so only kg==0 contributes bias + x term.
    const float m = (kg == 0) ? 1.f : 0.f;
    float wih_m[4], bias_m[4], wout[4];
    #pragma unroll
    for (int r = 0; r < 4; ++r) {
        wih_m[r]  = m * W_ih[4 * og + r];
        bias_m[r] = m * (b_ih[4 * og + r] + b_hh[4 * og + r]);
        wout[r]   = W_out[4 * og + r];
    }

    const bool writer = ((lane >> 4) == kg);   // og>>2 == kg: 16 lanes, each og once

    if (lane < 16) hA[lane] = float4{0.f, 0.f, 0.f, 0.f};   // h0 = 0

    const float* xs = reinterpret_cast<const float*>(xs4);

    float4 hq;   // this lane's 4 tanh outputs (replicated across the quad)

    auto halfstep = [&](float xv, const float4* __restrict__ hr,
                        float4* __restrict__ hw) {
        float a0 = fmaf(xv, wih_m[0], bias_m[0]);
        float a1 = fmaf(xv, wih_m[1], bias_m[1]);
        float a2 = fmaf(xv, wih_m[2], bias_m[2]);
        float a3 = fmaf(xv, wih_m[3], bias_m[3]);
        #pragma unroll
        for (int c = 0; c < 4; ++c) {
            const float4 hv = hr[4 * kg + c];   // ds_read_b128, 64 B/lane total
            a0 = fmaf(hv.x, w[0][c].x, a0); a0 = fmaf(hv.y, w[0][c].y, a0);
            a0 = fmaf(hv.z, w[0][c].z, a0); a0 = fmaf(hv.w, w[0][c].w, a0);
            a1 = fmaf(hv.x, w[1][c].x, a1); a1 = fmaf(hv.y, w[1][c].y, a1);
            a1 = fmaf(hv.z, w[1][c].z, a1); a1 = fmaf(hv.w, w[1][c].w, a1);
            a2 = fmaf(hv.x, w[2][c].x, a2); a2 = fmaf(hv.y, w[2][c].y, a2);
            a2 = fmaf(hv.z, w[2][c].z, a2); a2 = fmaf(hv.w, w[2][c].w, a2);
            a3 = fmaf(hv.x, w[3][c].x, a3); a3 = fmaf(hv.y, w[3][c].y, a3);
            a3 = fmaf(hv.z, w[3][c].z, a3); a3 = fmaf(hv.w, w[3][c].w, a3);
        }
        // Reduce the 4 k-partials across the quad (VALU DPP, no LDS).
        a0 = dpp_add_xor1(a0); a0 = dpp_add_xor2(a0);
        a1 = dpp_add_xor1(a1); a1 = dpp_add_xor2(a1);
        a2 = dpp_add_xor1(a2); a2 = dpp_add_xor2(a2);
        a3 = dpp_add_xor1(a3); a3 = dpp_add_xor2(a3);
        hq.x = tanh_fast(a0);
        hq.y = tanh_fast(a1);
        hq.z = tanh_fast(a2);
        hq.w = tanh_fast(a3);
        if (writer) hw[og] = hq;   // one ds_write_b128, banks 4og: conflict-free
    };

    for (int t = 0; t < T_STEPS; t += 2) {
        halfstep(xs[t],     hA, hB);
        halfstep(xs[t + 1], hB, hA);
    }

    // out[b] = sigmoid(sum_i h[i] * W_out[i] + b_out)
    // hq is replicated within each quad; butterfly over og bits only.
    float p = hq.x * wout[0] + hq.y * wout[1] + hq.z * wout[2] + hq.w * wout[3];
    #pragma unroll
    for (int off = 4; off <= 32; off <<= 1)
        p += __shfl_xor(p, off);
    if (lane == 0)
        out[b] = 1.f / (1.f + __expf(-(p + b_out[0])));
}

extern "C" void kernel_launch(void* const* d_in, const int* in_sizes, int n_in,
                              void* d_out, int out_size, void* d_ws, size_t ws_size,
                              hipStream_t stream)
{
    const float* x     = (const float*)d_in[0];
    const float* W_ih  = (const float*)d_in[1];
    const float* W_hh  = (const float*)d_in[2];
    const float* b_ih  = (const float*)d_in[3];
    const float* b_hh  = (const float*)d_in[4];
    const float* W_out = (const float*)d_in[5];
    const float* b_out = (const float*)d_in[6];
    float* out = (float*)d_out;

    const int B = out_size;  // one wave per chain
    rnn_fused<<<B, 64, 0, stream>>>(x, W_ih, W_hh, b_ih, b_hh, W_out, b_out, out);
}

// Round 4
// 266.795 us; speedup vs baseline: 1.6717x; 1.4614x over previous
//
#include <hip/hip_runtime.h>

// RNN: B=2048 chains, T=1024 steps, H=64, I=1. One wave per chain.
// Lane (og=lane>>2, kg=lane&3): 4 outputs x 16-k slice, W tile in regs with
// ROTATED row order (reg r = output (kg+r)&3), so a 3-op DPP ring
// reduce-scatters the quad partials and lane q ends with exactly output
// 4og+q's sum -> ONE tanh per lane, full-wave ds_write h[lane].
// Single wave per block -> DS in-order, no barriers.

constexpr int T_STEPS = 1024;
constexpr int H = 64;

__device__ __forceinline__ float dpp_rotfwd_add(float t, float a) {
    // within each quad: lane q receives t from lane (q+1)&3, then adds a.
    // quad_perm sel [1,2,3,0] = 0x39.
    int y = __builtin_amdgcn_mov_dpp(__builtin_bit_cast(int, t), 0x39, 0xF, 0xF, true);
    return __builtin_bit_cast(float, y) + a;
}

__device__ __forceinline__ float tanh_fast(float s) {
    // tanh(s) = 1 - 2/(exp(2s)+1); saturates correctly for |s| large.
    const float e = __expf(2.f * s);
    return 1.f - 2.f * __builtin_amdgcn_rcpf(e + 1.f);
}

__global__ __launch_bounds__(64, 2) void rnn_fused(
    const float* __restrict__ x,      // [B, T, 1]
    const float* __restrict__ W_ih,   // [H, 1]
    const float* __restrict__ W_hh,   // [H, H] row-major
    const float* __restrict__ b_ih,   // [H]
    const float* __restrict__ b_hh,   // [H]
    const float* __restrict__ W_out,  // [1, H]
    const float* __restrict__ b_out,  // [1]
    float* __restrict__ out)          // [B, 1]
{
    const int b    = blockIdx.x;
    const int lane = threadIdx.x;     // 0..63
    const int og   = lane >> 2;
    const int kg   = lane & 3;        // k-slice [16kg, 16kg+16)

    __shared__ float4 xs4[T_STEPS / 4];   // 4 KiB: x[b, :]
    __shared__ float  hA[H];
    __shared__ float  hB[H];

    // Stage x[b, :], coalesced float4.
    const float4* xrow = reinterpret_cast<const float4*>(x + (size_t)b * T_STEPS);
    #pragma unroll
    for (int k = 0; k < T_STEPS / 4 / 64; ++k)
        xs4[lane + 64 * k] = xrow[lane + 64 * k];

    // W tile, rotated rows: reg r holds W_hh row (4og + ((kg+r)&3)),
    // cols [16kg, 16kg+16). P[q][o] accumulates in reg (o-q)&3 of lane q.
    float4 w[4][4];
    #pragma unroll
    for (int r = 0; r < 4; ++r) {
        const int row = 4 * og + ((kg + r) & 3);
        #pragma unroll
        for (int c = 0; c < 4; ++c)
            w[r][c] = *reinterpret_cast<const float4*>(
                W_hh + (size_t)row * H + 16 * kg + 4 * c);
    }

    // Per-lane scalars for OUR output (index = lane).
    const float wih  = W_ih[lane];
    const float bias = b_ih[lane] + b_hh[lane];
    const float wout = W_out[lane];

    hA[lane] = 0.f;   // h0 = 0

    float hn = 0.f;

    auto step = [&](float xv, const float* __restrict__ hr,
                    float* __restrict__ hw) {
        const float4* h4 = reinterpret_cast<const float4*>(hr) + 4 * kg;
        // 8 accumulators: l* over c=0,1; m* over c=2,3 (dep chains of 8).
        // l0 seeds with xp for OUR output: a0 is added at the home lane on
        // the final ring pass, so the seed lands in the right output.
        float l0 = fmaf(xv, wih, bias), l1 = 0.f, l2 = 0.f, l3 = 0.f;
        float m0 = 0.f, m1 = 0.f, m2 = 0.f, m3 = 0.f;
        #pragma unroll
        for (int c = 0; c < 2; ++c) {
            const float4 hv = h4[c];            // ds_read_b128
            l0 = fmaf(hv.x, w[0][c].x, l0); l0 = fmaf(hv.y, w[0][c].y, l0);
            l0 = fmaf(hv.z, w[0][c].z, l0); l0 = fmaf(hv.w, w[0][c].w, l0);
            l1 = fmaf(hv.x, w[1][c].x, l1); l1 = fmaf(hv.y, w[1][c].y, l1);
            l1 = fmaf(hv.z, w[1][c].z, l1); l1 = fmaf(hv.w, w[1][c].w, l1);
            l2 = fmaf(hv.x, w[2][c].x, l2); l2 = fmaf(hv.y, w[2][c].y, l2);
            l2 = fmaf(hv.z, w[2][c].z, l2); l2 = fmaf(hv.w, w[2][c].w, l2);
            l3 = fmaf(hv.x, w[3][c].x, l3); l3 = fmaf(hv.y, w[3][c].y, l3);
            l3 = fmaf(hv.z, w[3][c].z, l3); l3 = fmaf(hv.w, w[3][c].w, l3);
        }
        #pragma unroll
        for (int c = 2; c < 4; ++c) {
            const float4 hv = h4[c];
            m0 = fmaf(hv.x, w[0][c].x, m0); m0 = fmaf(hv.y, w[0][c].y, m0);
            m0 = fmaf(hv.z, w[0][c].z, m0); m0 = fmaf(hv.w, w[0][c].w, m0);
            m1 = fmaf(hv.x, w[1][c].x, m1); m1 = fmaf(hv.y, w[1][c].y, m1);
            m1 = fmaf(hv.z, w[1][c].z, m1); m1 = fmaf(hv.w, w[1][c].w, m1);
            m2 = fmaf(hv.x, w[2][c].x, m2); m2 = fmaf(hv.y, w[2][c].y, m2);
            m2 = fmaf(hv.z, w[2][c].z, m2); m2 = fmaf(hv.w, w[2][c].w, m2);
            m3 = fmaf(hv.x, w[3][c].x, m3); m3 = fmaf(hv.y, w[3][c].y, m3);
            m3 = fmaf(hv.z, w[3][c].z, m3); m3 = fmaf(hv.w, w[3][c].w, m3);
        }
        const float a0 = l0 + m0, a1 = l1 + m1, a2 = l2 + m2, a3 = l3 + m3;
        // Reduce-scatter ring (3 fused dpp-adds). After pass 3, lane q holds
        // the complete sum for output 4og+q:
        //   t=a1 -> +a2 (out q+2, 2 lanes) -> +a3 (out q+3, 3 lanes)
        //        -> +a0 (out q, all 4 lanes + xp seed).
        float t = a1;
        t = dpp_rotfwd_add(t, a2);
        t = dpp_rotfwd_add(t, a3);
        t = dpp_rotfwd_add(t, a0);
        hn = tanh_fast(t);
        hw[lane] = hn;                          // stride-4 ds_write_b32: free
    };

    const float* xs = reinterpret_cast<const float*>(xs4);
    #pragma unroll 1
    for (int t4 = 0; t4 < T_STEPS / 4; ++t4) {
        const float4 xq = xs4[t4];              // uniform ds_read_b128
        step(xq.x, hA, hB);
        step(xq.y, hB, hA);
        step(xq.z, hA, hB);
        step(xq.w, hB, hA);
    }
    (void)xs;

    // out[b] = sigmoid(sum_i h[i] * W_out[i] + b_out); h[i] lives in lane i.
    float p = hn * wout;
    #pragma unroll
    for (int off = 1; off <= 32; off <<= 1)
        p += __shfl_xor(p, off);
    if (lane == 0)
        out[b] = 1.f / (1.f + __expf(-(p + b_out[0])));
}

extern "C" void kernel_launch(void* const* d_in, const int* in_sizes, int n_in,
                              void* d_out, int out_size, void* d_ws, size_t ws_size,
                              hipStream_t stream)
{
    const float* x     = (const float*)d_in[0];
    const float* W_ih  = (const float*)d_in[1];
    const float* W_hh  = (const float*)d_in[2];
    const float* b_ih  = (const float*)d_in[3];
    const float* b_hh  = (const float*)d_in[4];
    const float* W_out = (const float*)d_in[5];
    const float* b_out = (const float*)d_in[6];
    float* out = (float*)d_out;

    const int B = out_size;  // one wave per chain
    rnn_fused<<<B, 64, 0, stream>>>(x, W_ih, W_hh, b_ih, b_hh, W_out, b_out, out);
}

// Round 5
// 234.364 us; speedup vs baseline: 1.9030x; 1.1384x over previous
//
#include <hip/hip_runtime.h>

// RNN: B=2048 chains, T=1024 steps, H=64, I=1. One wave per chain.
// Round-5: VALU-issue-bound (VALUBusy 99%) -> cut instructions/step.
//  * v_pk_fma_f32 via float2 ext-vectors: 32 packed FMA instead of 64 scalar.
//  * W tile pinned in arch VGPRs with an empty asm "+v" barrier (round-4
//    showed VGPR_Count=48 < 64 -> W was NOT in arch VGPRs).
//  * Rotated-row W layout + 3-op DPP ring reduce-scatter (round 4), one
//    tanh per lane, full-wave ds_write h[lane]. No barriers (1 wave/block).

constexpr int T_STEPS = 1024;
constexpr int H = 64;

typedef float v2f __attribute__((ext_vector_type(2)));
typedef float v4f __attribute__((ext_vector_type(4)));

__device__ __forceinline__ float dpp_rotfwd_add(float t, float a) {
    // within each quad: lane q receives t from lane (q+1)&3, then adds a.
    int y = __builtin_amdgcn_mov_dpp(__builtin_bit_cast(int, t), 0x39, 0xF, 0xF, true);
    return __builtin_bit_cast(float, y) + a;
}

__device__ __forceinline__ float tanh_fast(float s) {
    // tanh(s) = 1 - 2/(exp(2s)+1); saturates correctly for |s| large.
    const float e = __expf(2.f * s);
    return 1.f - 2.f * __builtin_amdgcn_rcpf(e + 1.f);
}

__global__ __launch_bounds__(64, 2) void rnn_fused(
    const float* __restrict__ x,      // [B, T, 1]
    const float* __restrict__ W_ih,   // [H, 1]
    const float* __restrict__ W_hh,   // [H, H] row-major
    const float* __restrict__ b_ih,   // [H]
    const float* __restrict__ b_hh,   // [H]
    const float* __restrict__ W_out,  // [1, H]
    const float* __restrict__ b_out,  // [1]
    float* __restrict__ out)          // [B, 1]
{
    const int b    = blockIdx.x;
    const int lane = threadIdx.x;     // 0..63
    const int og   = lane >> 2;
    const int kg   = lane & 3;        // k-slice [16kg, 16kg+16)

    __shared__ v4f xs4[T_STEPS / 4];  // 4 KiB: x[b, :]
    __shared__ v4f hA4[H / 4];
    __shared__ v4f hB4[H / 4];

    // Stage x[b, :], coalesced float4.
    const v4f* xrow = reinterpret_cast<const v4f*>(x + (size_t)b * T_STEPS);
    #pragma unroll
    for (int k = 0; k < T_STEPS / 4 / 64; ++k)
        xs4[lane + 64 * k] = xrow[lane + 64 * k];

    // W tile as float2 pairs, rotated rows: row index for slot r is
    // 4og + ((kg+r)&3); cols [16kg,16kg+16) as 8 even/odd pairs.
    v2f w2[4][8];
    #pragma unroll
    for (int r = 0; r < 4; ++r) {
        const int row = 4 * og + ((kg + r) & 3);
        const float* src = W_hh + (size_t)row * H + 16 * kg;
        #pragma unroll
        for (int c2 = 0; c2 < 8; ++c2)
            w2[r][c2] = *reinterpret_cast<const v2f*>(src + 2 * c2);
    }
    // Pin W in arch VGPRs; block rematerialization / AGPR parking.
    #pragma unroll
    for (int r = 0; r < 4; ++r)
        #pragma unroll
        for (int c2 = 0; c2 < 8; ++c2)
            asm volatile("" : "+v"(w2[r][c2]));

    // Per-lane scalars for OUR output (index = lane).
    const float wih  = W_ih[lane];
    const float bias = b_ih[lane] + b_hh[lane];
    const float wout = W_out[lane];

    reinterpret_cast<float*>(hA4)[lane] = 0.f;   // h0 = 0

    float hn = 0.f;

    auto step = [&](float xv, const v4f* __restrict__ hr,
                    float* __restrict__ hw) {
        const v4f* h4 = hr + 4 * kg;
        // 8 packed accumulators (dep chains of 4). Seed (xp for OUR output)
        // folded into accL[0].x: a0 is added at the home lane on the final
        // ring pass, so it lands in the right output.
        v2f accL[4], accM[4];
        accL[0] = v2f{fmaf(xv, wih, bias), 0.f};
        accL[1] = v2f{0.f, 0.f}; accL[2] = v2f{0.f, 0.f}; accL[3] = v2f{0.f, 0.f};
        accM[0] = v2f{0.f, 0.f}; accM[1] = v2f{0.f, 0.f};
        accM[2] = v2f{0.f, 0.f}; accM[3] = v2f{0.f, 0.f};
        #pragma unroll
        for (int c = 0; c < 2; ++c) {
            const v4f hv = h4[c];                           // ds_read_b128
            const v2f hlo = __builtin_shufflevector(hv, hv, 0, 1);
            const v2f hhi = __builtin_shufflevector(hv, hv, 2, 3);
            #pragma unroll
            for (int r = 0; r < 4; ++r) {
                accL[r] = __builtin_elementwise_fma(hlo, w2[r][2 * c],     accL[r]);
                accM[r] = __builtin_elementwise_fma(hhi, w2[r][2 * c + 1], accM[r]);
            }
        }
        #pragma unroll
        for (int c = 2; c < 4; ++c) {
            const v4f hv = h4[c];
            const v2f hlo = __builtin_shufflevector(hv, hv, 0, 1);
            const v2f hhi = __builtin_shufflevector(hv, hv, 2, 3);
            #pragma unroll
            for (int r = 0; r < 4; ++r) {
                accL[r] = __builtin_elementwise_fma(hlo, w2[r][2 * c],     accL[r]);
                accM[r] = __builtin_elementwise_fma(hhi, w2[r][2 * c + 1], accM[r]);
            }
        }
        // Merge packed halves: 4 pk_add + 4 scalar adds.
        float a[4];
        #pragma unroll
        for (int r = 0; r < 4; ++r) {
            const v2f s2 = accL[r] + accM[r];
            a[r] = s2.x + s2.y;
        }
        // Reduce-scatter ring (3 fused dpp-adds): lane q ends with the
        // complete sum for output 4og+q (incl. xp seed via a[0]).
        float t = a[1];
        t = dpp_rotfwd_add(t, a[2]);
        t = dpp_rotfwd_add(t, a[3]);
        t = dpp_rotfwd_add(t, a[0]);
        hn = tanh_fast(t);
        hw[lane] = hn;                                      // stride-4: free
    };

    #pragma unroll 1
    for (int t4 = 0; t4 < T_STEPS / 4; ++t4) {
        const v4f xq = xs4[t4];                             // uniform b128 read
        step(xq.x, hA4, reinterpret_cast<float*>(hB4));
        step(xq.y, hB4, reinterpret_cast<float*>(hA4));
        step(xq.z, hA4, reinterpret_cast<float*>(hB4));
        step(xq.w, hB4, reinterpret_cast<float*>(hA4));
    }

    // out[b] = sigmoid(sum_i h[i] * W_out[i] + b_out); h[i] lives in lane i.
    float p = hn * wout;
    #pragma unroll
    for (int off = 1; off <= 32; off <<= 1)
        p += __shfl_xor(p, off);
    if (lane == 0)
        out[b] = 1.f / (1.f + __expf(-(p + b_out[0])));
}

extern "C" void kernel_launch(void* const* d_in, const int* in_sizes, int n_in,
                              void* d_out, int out_size, void* d_ws, size_t ws_size,
                              hipStream_t stream)
{
    const float* x     = (const float*)d_in[0];
    const float* W_ih  = (const float*)d_in[1];
    const float* W_hh  = (const float*)d_in[2];
    const float* b_ih  = (const float*)d_in[3];
    const float* b_hh  = (const float*)d_in[4];
    const float* W_out = (const float*)d_in[5];
    const float* b_out = (const float*)d_in[6];
    float* out = (float*)d_out;

    const int B = out_size;  // one wave per chain
    rnn_fused<<<B, 64, 0, stream>>>(x, W_ih, W_hh, b_ih, b_hh, W_out, b_out, out);
}